// Round 4
// baseline (116.162 us; speedup 1.0000x reference)
//
#include <hip/hip_runtime.h>

// Elementwise J2(x), x in [0, 30], fp32. Direct-J2 approximations:
//   x < 8 : Maclaurin series  J2 = u * sum_{k=0..11} (-1)^k u^k/(k!(k+2)!),
//           u = (x/2)^2.  Truncation ~1.1e-4 at x=8 (threshold 9.7e-3).
//   x >= 8: Hankel asymptotic (mu=16), trimmed:
//           J2 = sqrt(2/(pi x)) [P2 cos chi - Q2 sin chi], chi = x - 5pi/4
//           P2 = 1 - 1.28174e-2*yy          (dropped yy^2 term, +2e-5 err)
//           Q2 = z*(0.234375 + 6.00815e-4*yy)  (dropped yy^2 term, +4e-6)
//           z = 8/x, yy = z^2.  Error vs true J2 at x=8: ~4e-4. OK.
// Round-4 changes vs round 3:
//   - 4x unroll, all 4 float4 loads issued before any compute (deeper MLP)
//   - phase in revolutions: chi_rev = fma(x, 1/2pi, -0.625); v_sin/v_cos
//     directly (valid domain +-256 rev; here |chi_rev| < 5) — saves the
//     radians detour inside __sincosf
//   - no fmax guard on the big path: x<8 lanes may compute inf/NaN there,
//     which the final per-lane select (v_cndmask) discards — bitwise safe
//   - series truncated at k=11, P2/Q2 last terms dropped (~25% fewer slots)

typedef float vf4 __attribute__((ext_vector_type(4)));

__device__ __forceinline__ float bessj2_fast(float x) {
    // ---- small path: power series in u = (x/2)^2 ----
    float h = 0.5f * x;
    float u = h * h;
    float s;
    s = 4.02324e-18f;                       // c11 (sign folded: odd k negative)
    s = fmaf(s, u, -5.75302e-16f);          // careful: Horner from c11 down
    // NOTE: signs: c_k alternate (-1)^k; k=11 -> negative. Start with -c11:
    s = -4.02324e-18f;
    s = fmaf(s, u,  5.75302e-16f);
    s = fmaf(s, u, -6.90369e-14f);
    s = fmaf(s, u,  6.83466e-12f);
    s = fmaf(s, u, -5.46771e-10f);
    s = fmaf(s, u,  3.44466e-08f);
    s = fmaf(s, u, -1.65344e-06f);
    s = fmaf(s, u,  5.78704e-05f);
    s = fmaf(s, u, -1.38889e-03f);
    s = fmaf(s, u,  2.08333e-02f);
    s = fmaf(s, u, -1.66667e-01f);
    s = fmaf(s, u,  0.5f);
    float j2_small = u * s;

    // ---- big path: trimmed Hankel asymptotic, n = 2 ----
    float r    = __builtin_amdgcn_rsqf(x);       // 1/sqrt(x); x<8 lanes unused
    float rinv = r * r;                          // 1/x
    float amp  = 0.797884561f * r;               // sqrt(2/(pi x))
    float z    = 8.0f * rinv;
    float yy   = z * z;
    // chi = x - 5pi/4; in revolutions: chi_rev = x/(2pi) - 0.625
    float chi_rev = fmaf(x, 0.159154943f, -0.625f);
    float sc = __builtin_amdgcn_sinf(chi_rev);   // sin(2*pi*chi_rev) = sin(chi)
    float cc = __builtin_amdgcn_cosf(chi_rev);
    float p = fmaf(yy, -1.28174e-02f, 1.0f);
    float q = z * fmaf(yy, 6.00815e-04f, 0.234375f);
    float j2_big = amp * fmaf(cc, p, -(sc * q));

    return (x < 8.0f) ? j2_small : j2_big;
}

__device__ __forceinline__ vf4 j2_vec(vf4 v) {
    vf4 r;
    r.x = bessj2_fast(v.x);
    r.y = bessj2_fast(v.y);
    r.z = bessj2_fast(v.z);
    r.w = bessj2_fast(v.w);
    return r;
}

__global__ __launch_bounds__(256)
void j2_vec4_kernel(const float* __restrict__ in, float* __restrict__ out,
                    int n4) {
    const vf4* in4  = reinterpret_cast<const vf4*>(in);
    vf4*       out4 = reinterpret_cast<vf4*>(out);
    int idx    = blockIdx.x * blockDim.x + threadIdx.x;
    int stride = gridDim.x * blockDim.x;

    int i = idx;
    // 4x unrolled: all four loads issued before any compute.
    for (; i + 3 * stride < n4; i += 4 * stride) {
        vf4 a0 = __builtin_nontemporal_load(in4 + i);
        vf4 a1 = __builtin_nontemporal_load(in4 + i + stride);
        vf4 a2 = __builtin_nontemporal_load(in4 + i + 2 * stride);
        vf4 a3 = __builtin_nontemporal_load(in4 + i + 3 * stride);
        __builtin_nontemporal_store(j2_vec(a0), out4 + i);
        __builtin_nontemporal_store(j2_vec(a1), out4 + i + stride);
        __builtin_nontemporal_store(j2_vec(a2), out4 + i + 2 * stride);
        __builtin_nontemporal_store(j2_vec(a3), out4 + i + 3 * stride);
    }
    for (; i < n4; i += stride) {
        vf4 a = __builtin_nontemporal_load(in4 + i);
        __builtin_nontemporal_store(j2_vec(a), out4 + i);
    }
}

__global__ __launch_bounds__(256)
void j2_tail_kernel(const float* __restrict__ in, float* __restrict__ out,
                    int start, int n) {
    int i = start + blockIdx.x * blockDim.x + threadIdx.x;
    if (i < n) out[i] = bessj2_fast(in[i]);
}

extern "C" void kernel_launch(void* const* d_in, const int* in_sizes, int n_in,
                              void* d_out, int out_size, void* d_ws, size_t ws_size,
                              hipStream_t stream) {
    const float* in  = (const float*)d_in[0];
    float*       out = (float*)d_out;
    int n  = in_sizes[0];
    int n4 = n >> 2;

    if (n4 > 0) {
        int blocks = (n4 + 255) / 256;
        if (blocks > 2048) blocks = 2048;   // 2048*256 threads = 8192 waves
        j2_vec4_kernel<<<blocks, 256, 0, stream>>>(in, out, n4);
    }
    int rem_start = n4 << 2;
    int rem = n - rem_start;
    if (rem > 0) {
        j2_tail_kernel<<<(rem + 255) / 256, 256, 0, stream>>>(in, out,
                                                              rem_start, n);
    }
}

// Round 5
// 102.448 us; speedup vs baseline: 1.1339x; 1.1339x over previous
//
#include <hip/hip_runtime.h>

// Elementwise J2(x), x in [0, 30], fp32. Direct-J2 approximations:
//   x < 8 : Maclaurin series  J2 = u * sum_{k=0..11} (-1)^k u^k/(k!(k+2)!),
//           u = (x/2)^2.  Truncation ~1.1e-4 at x=8 (threshold 9.7e-3).
//   x >= 8: Hankel asymptotic (mu=16), trimmed:
//           J2 = sqrt(2/(pi x)) [P2 cos chi - Q2 sin chi], chi = x - 5pi/4
//           P2 = 1 - 1.28174e-2*yy            (yy^2 term dropped, +2e-5)
//           Q2 = z*(0.234375 + 6.00815e-4*yy) (yy^2 term dropped, +4e-6)
//           z = 8/x, yy = z^2.  Total error vs true J2 <~ 4e-4.
//
// Round-5: structure reverted to the round-3 winner (2x unroll, both float4
// loads issued before compute — measured 100.8us; the 4x variant regressed
// to 116us via register-lifetime/scheduling pressure at full occupancy).
// Kept the round-4 math trims:
//   - one v_rsq: r=rsq(x); 1/x=r*r; sqrt(2/(pi x))=sqrt(2/pi)*r
//   - phase in revolutions: chi_rev = fma(x, 1/(2pi), -0.625), then
//     v_sin/v_cos directly (hardware takes revolutions; |chi_rev| < 5)
//   - no fmax guard: x<8 lanes' big-path garbage is discarded by cndmask
//   - k=11 series, trimmed P2/Q2

typedef float vf4 __attribute__((ext_vector_type(4)));

__device__ __forceinline__ float bessj2_fast(float x) {
    // ---- small path: power series in u = (x/2)^2, Horner k=11..0 ----
    float h = 0.5f * x;
    float u = h * h;
    float s;
    s = -4.02324e-18f;                     // -1/(11!*13!) (k=11, sign (-1)^k)
    s = fmaf(s, u,  5.75302e-16f);
    s = fmaf(s, u, -6.90369e-14f);
    s = fmaf(s, u,  6.83466e-12f);
    s = fmaf(s, u, -5.46771e-10f);
    s = fmaf(s, u,  3.44466e-08f);
    s = fmaf(s, u, -1.65344e-06f);
    s = fmaf(s, u,  5.78704e-05f);
    s = fmaf(s, u, -1.38889e-03f);
    s = fmaf(s, u,  2.08333e-02f);
    s = fmaf(s, u, -1.66667e-01f);
    s = fmaf(s, u,  0.5f);
    float j2_small = u * s;

    // ---- big path: trimmed Hankel asymptotic, n = 2 ----
    float r    = __builtin_amdgcn_rsqf(x);       // 1/sqrt(x); junk for x<8 lanes
    float rinv = r * r;                          // 1/x
    float amp  = 0.797884561f * r;               // sqrt(2/(pi x))
    float z    = 8.0f * rinv;
    float yy   = z * z;
    float chi_rev = fmaf(x, 0.159154943f, -0.625f);  // (x - 5pi/4) / 2pi
    float sc = __builtin_amdgcn_sinf(chi_rev);
    float cc = __builtin_amdgcn_cosf(chi_rev);
    float p = fmaf(yy, -1.28174e-02f, 1.0f);
    float q = z * fmaf(yy, 6.00815e-04f, 0.234375f);
    float j2_big = amp * fmaf(cc, p, -(sc * q));

    return (x < 8.0f) ? j2_small : j2_big;
}

__device__ __forceinline__ vf4 j2_vec(vf4 v) {
    vf4 r;
    r.x = bessj2_fast(v.x);
    r.y = bessj2_fast(v.y);
    r.z = bessj2_fast(v.z);
    r.w = bessj2_fast(v.w);
    return r;
}

__global__ __launch_bounds__(256)
void j2_vec4_kernel(const float* __restrict__ in, float* __restrict__ out,
                    int n4) {
    const vf4* in4  = reinterpret_cast<const vf4*>(in);
    vf4*       out4 = reinterpret_cast<vf4*>(out);
    int idx    = blockIdx.x * blockDim.x + threadIdx.x;
    int stride = gridDim.x * blockDim.x;

    int i = idx;
    // 2x unrolled: both loads issued before any compute (round-3 structure).
    for (; i + stride < n4; i += 2 * stride) {
        vf4 a = __builtin_nontemporal_load(in4 + i);
        vf4 b = __builtin_nontemporal_load(in4 + i + stride);
        vf4 ra = j2_vec(a);
        vf4 rb = j2_vec(b);
        __builtin_nontemporal_store(ra, out4 + i);
        __builtin_nontemporal_store(rb, out4 + i + stride);
    }
    if (i < n4) {
        vf4 a = __builtin_nontemporal_load(in4 + i);
        __builtin_nontemporal_store(j2_vec(a), out4 + i);
    }
}

__global__ __launch_bounds__(256)
void j2_tail_kernel(const float* __restrict__ in, float* __restrict__ out,
                    int start, int n) {
    int i = start + blockIdx.x * blockDim.x + threadIdx.x;
    if (i < n) out[i] = bessj2_fast(in[i]);
}

extern "C" void kernel_launch(void* const* d_in, const int* in_sizes, int n_in,
                              void* d_out, int out_size, void* d_ws, size_t ws_size,
                              hipStream_t stream) {
    const float* in  = (const float*)d_in[0];
    float*       out = (float*)d_out;
    int n  = in_sizes[0];
    int n4 = n >> 2;

    if (n4 > 0) {
        int blocks = (n4 + 255) / 256;
        if (blocks > 2048) blocks = 2048;   // 2048*256 threads = 8192 waves
        j2_vec4_kernel<<<blocks, 256, 0, stream>>>(in, out, n4);
    }
    int rem_start = n4 << 2;
    int rem = n - rem_start;
    if (rem > 0) {
        j2_tail_kernel<<<(rem + 255) / 256, 256, 0, stream>>>(in, out,
                                                              rem_start, n);
    }
}

// Round 6
// 87.607 us; speedup vs baseline: 1.3259x; 1.1694x over previous
//
#include <hip/hip_runtime.h>

// Elementwise J2(x), x in [0, 30], fp32. Direct-J2 approximations:
//   x < 8 : Maclaurin series  J2 = u * sum_{k=0..11} (-1)^k u^k/(k!(k+2)!),
//           u = (x/2)^2.  Truncation ~1.1e-4 at x=8 (threshold 9.7e-3).
//   x >= 8: Hankel asymptotic (mu=16), trimmed:
//           J2 = sqrt(2/(pi x)) [P2 cos chi - Q2 sin chi], chi = x - 5pi/4
//           P2 = 1 - 1.28174e-2*yy            (yy^2 term dropped)
//           Q2 = z*(0.234375 + 6.00815e-4*yy) (yy^2 term dropped)
//           z = 8/x, yy = z^2.  Total error vs true J2 <~ 4e-4.
//
// Round-6 structure: ONE-SHOT kernel, no grid-stride loop. Theory: in the
// looped version each iteration's nontemporal stores force an
// s_waitcnt vmcnt(0) before their data VGPRs are reused by the next
// iteration -> per-wave stall on store drain. One-shot threads never reuse
// store registers: stores drain past s_endpgm, waves retire, CU backfills
// with fresh waves that issue loads immediately. 2 tiles/thread keeps the
// proven 2-deep load burst (round 3); second tile at +total_threads so both
// loads are wave-coalesced.

typedef float vf4 __attribute__((ext_vector_type(4)));

__device__ __forceinline__ float bessj2_fast(float x) {
    // ---- small path: power series in u = (x/2)^2, Horner k=11..0 ----
    float h = 0.5f * x;
    float u = h * h;
    float s;
    s = -4.02324e-18f;
    s = fmaf(s, u,  5.75302e-16f);
    s = fmaf(s, u, -6.90369e-14f);
    s = fmaf(s, u,  6.83466e-12f);
    s = fmaf(s, u, -5.46771e-10f);
    s = fmaf(s, u,  3.44466e-08f);
    s = fmaf(s, u, -1.65344e-06f);
    s = fmaf(s, u,  5.78704e-05f);
    s = fmaf(s, u, -1.38889e-03f);
    s = fmaf(s, u,  2.08333e-02f);
    s = fmaf(s, u, -1.66667e-01f);
    s = fmaf(s, u,  0.5f);
    float j2_small = u * s;

    // ---- big path: trimmed Hankel asymptotic, n = 2 ----
    float r    = __builtin_amdgcn_rsqf(x);       // junk for x<8 lanes, discarded
    float rinv = r * r;                          // 1/x
    float amp  = 0.797884561f * r;               // sqrt(2/(pi x))
    float z    = 8.0f * rinv;
    float yy   = z * z;
    float chi_rev = fmaf(x, 0.159154943f, -0.625f);  // (x - 5pi/4) / 2pi
    float sc = __builtin_amdgcn_sinf(chi_rev);
    float cc = __builtin_amdgcn_cosf(chi_rev);
    float p = fmaf(yy, -1.28174e-02f, 1.0f);
    float q = z * fmaf(yy, 6.00815e-04f, 0.234375f);
    float j2_big = amp * fmaf(cc, p, -(sc * q));

    return (x < 8.0f) ? j2_small : j2_big;
}

__device__ __forceinline__ vf4 j2_vec(vf4 v) {
    vf4 r;
    r.x = bessj2_fast(v.x);
    r.y = bessj2_fast(v.y);
    r.z = bessj2_fast(v.z);
    r.w = bessj2_fast(v.w);
    return r;
}

// One-shot: each thread processes exactly 2 vf4 tiles (i0 and i0+nthreads).
__global__ __launch_bounds__(256)
void j2_flat2_kernel(const float* __restrict__ in, float* __restrict__ out,
                     int n4) {
    const vf4* in4  = reinterpret_cast<const vf4*>(in);
    vf4*       out4 = reinterpret_cast<vf4*>(out);
    int nthreads = gridDim.x * blockDim.x;
    int i0 = blockIdx.x * blockDim.x + threadIdx.x;
    int i1 = i0 + nthreads;

    bool v0 = i0 < n4;
    bool v1 = i1 < n4;
    vf4 a{}, b{};
    if (v0) a = __builtin_nontemporal_load(in4 + i0);
    if (v1) b = __builtin_nontemporal_load(in4 + i1);
    vf4 ra = j2_vec(a);
    vf4 rb = j2_vec(b);
    if (v0) __builtin_nontemporal_store(ra, out4 + i0);
    if (v1) __builtin_nontemporal_store(rb, out4 + i1);
}

__global__ __launch_bounds__(256)
void j2_tail_kernel(const float* __restrict__ in, float* __restrict__ out,
                    int start, int n) {
    int i = start + blockIdx.x * blockDim.x + threadIdx.x;
    if (i < n) out[i] = bessj2_fast(in[i]);
}

extern "C" void kernel_launch(void* const* d_in, const int* in_sizes, int n_in,
                              void* d_out, int out_size, void* d_ws, size_t ws_size,
                              hipStream_t stream) {
    const float* in  = (const float*)d_in[0];
    float*       out = (float*)d_out;
    int n  = in_sizes[0];
    int n4 = n >> 2;

    if (n4 > 0) {
        // 2 vf4 tiles per thread, one-shot (no loop).
        int threads_needed = (n4 + 1) / 2;
        int blocks = (threads_needed + 255) / 256;   // n=67.1M -> 32768 blocks
        j2_flat2_kernel<<<blocks, 256, 0, stream>>>(in, out, n4);
    }
    int rem_start = n4 << 2;
    int rem = n - rem_start;
    if (rem > 0) {
        j2_tail_kernel<<<(rem + 255) / 256, 256, 0, stream>>>(in, out,
                                                              rem_start, n);
    }
}